// Round 8
// baseline (660.686 us; speedup 1.0000x reference)
//
#include <hip/hip_runtime.h>
#include <hip/hip_bf16.h>

constexpr int NN  = 100000;
constexpr int NE  = 640000;
constexpr int D   = 128;
constexpr int BIN = 32;                // nodes per bin
constexpr int KB2 = NN / BIN;          // 3125 bins (exact)
constexpr int CPAD = 32;               // counter stride (ints) = 128 B line
constexpr int NHB = 64;                // histogram partial blocks
constexpr int LDG = 132;               // padded LDS row stride (floats)

typedef __attribute__((ext_vector_type(8))) short bf16x8;
typedef __attribute__((ext_vector_type(8))) unsigned short u16x8;
typedef __attribute__((ext_vector_type(4))) float f32x4;

__device__ __forceinline__ short f2bf(float f) {
    union { float f; unsigned u; } v; v.f = f;
    unsigned r = v.u + 0x7FFF + ((v.u >> 16) & 1);
    return (short)(r >> 16);
}
__device__ __forceinline__ float bf2f(short h) {
    union { unsigned u; float f; } v;
    v.u = ((unsigned)(unsigned short)h) << 16;
    return v.f;
}
__device__ __forceinline__ unsigned cvtpk(float a, float b) {
    union { __hip_bfloat162 h2; unsigned u; } cv;
    float2 f; f.x = a; f.y = b;
    cv.h2 = __float22bfloat162_rn(f);
    return cv.u;
}
__device__ __forceinline__ void pack_hilo(const float* v, bf16x8& hi, bf16x8& lo) {
#pragma unroll
    for (int i = 0; i < 4; ++i) {
        unsigned u = cvtpk(v[2 * i], v[2 * i + 1]);
        short h0 = (short)(u & 0xFFFF), h1 = (short)(u >> 16);
        hi[2 * i] = h0; hi[2 * i + 1] = h1;
        unsigned ul = cvtpk(v[2 * i] - bf2f(h0), v[2 * i + 1] - bf2f(h1));
        lo[2 * i] = (short)(ul & 0xFFFF); lo[2 * i + 1] = (short)(ul >> 16);
    }
}
__device__ __forceinline__ bf16x8 pack_bf8(const float* v) {
    bf16x8 o;
#pragma unroll
    for (int i = 0; i < 4; ++i) {
        unsigned u = cvtpk(v[2 * i], v[2 * i + 1]);
        o[2 * i] = (short)(u & 0xFFFF); o[2 * i + 1] = (short)(u >> 16);
    }
    return o;
}

// ---------------------------------------------------------------------------
// W pre-split: W[k][n] f32 -> Wt_hi[n][k], Wt_lo[n][k] bf16
// ---------------------------------------------------------------------------
__global__ __launch_bounds__(256) void k_wsplit(const float* __restrict__ W,
                                                short* __restrict__ Whi,
                                                short* __restrict__ Wlo) {
    for (int idx = blockIdx.x * 256 + threadIdx.x; idx < D * D; idx += gridDim.x * 256) {
        int n = idx >> 7, k = idx & 127;
        float w = W[k * D + n];
        short hi = f2bf(w);
        Whi[idx] = hi;
        Wlo[idx] = f2bf(w - bf2f(hi));
    }
}

// ---------------------------------------------------------------------------
// Partial histogram of bins: NHB blocks, LDS hist, NO global atomics.
// part[blk*KB2 + b] = count of edges in block blk's chunk with dst-bin b.
// ---------------------------------------------------------------------------
__global__ __launch_bounds__(256) void k_phist(const int* __restrict__ dst,
                                               int* __restrict__ part) {
    __shared__ int lh[KB2];  // 12.5 KB
    for (int i = threadIdx.x; i < KB2; i += 256) lh[i] = 0;
    __syncthreads();
    const int chunk = NE / NHB;                   // 10000
    const int e0 = blockIdx.x * chunk;
    for (int e = e0 + threadIdx.x; e < e0 + chunk; e += 256)
        atomicAdd(&lh[dst[e] >> 5], 1);
    __syncthreads();
    int* p = part + blockIdx.x * KB2;
    for (int i = threadIdx.x; i < KB2; i += 256) p[i] = lh[i];
}

// ---------------------------------------------------------------------------
// One-block scan: sum NHB partials per bin, exclusive-scan 3125 bins,
// write binoff[] and init the PADDED atomic cursors (cur[b*CPAD]).
// ---------------------------------------------------------------------------
__global__ __launch_bounds__(1024) void k_bscan(const int* __restrict__ part,
                                                int* __restrict__ binoff,
                                                int* __restrict__ cur) {
    int t = threadIdx.x, lane = t & 63;
    int c0[4]; int s = 0;
#pragma unroll
    for (int q = 0; q < 4; ++q) {
        int b = t * 4 + q;
        int v = 0;
        if (b < KB2)
            for (int p = 0; p < NHB; ++p) v += part[p * KB2 + b];
        c0[q] = v; s += v;
    }
    int incl = s;
#pragma unroll
    for (int sh = 1; sh < 64; sh <<= 1) {
        int u = __shfl_up(incl, sh, 64);
        if (lane >= sh) incl += u;
    }
    __shared__ int wt[16], wp[16];
    if (lane == 63) wt[t >> 6] = incl;
    __syncthreads();
    if (t == 0) { int run = 0; for (int i = 0; i < 16; ++i) { wp[i] = run; run += wt[i]; } }
    __syncthreads();
    int excl = incl - s + wp[t >> 6];
#pragma unroll
    for (int q = 0; q < 4; ++q) {
        int b = t * 4 + q;
        if (b < KB2) { binoff[b] = excl; cur[b * CPAD] = excl; excl += c0[q]; }
    }
    if (t == 0) binoff[KB2] = NE;
}

// ---------------------------------------------------------------------------
// Pass A (edge order, streaming): append bf16(relu(x[src]+ea)) to dst's bin.
// 16 threads/edge (16 B/lane); leader reserves slot on a 128B-padded counter
// (205 atomics/line -> no cross-XCD ping-pong), __shfl broadcasts the slot.
// Writes advance 3125 clustered fronts (L2 lines fill before eviction).
// ---------------------------------------------------------------------------
__global__ __launch_bounds__(256) void k_msg(const float* __restrict__ x,
                                             const int* __restrict__ src,
                                             const int* __restrict__ dst,
                                             const float* __restrict__ ea,
                                             int* __restrict__ cur,
                                             unsigned char* __restrict__ mdst,
                                             unsigned short* __restrict__ mbuf) {
    unsigned gid = blockIdx.x * 256 + threadIdx.x;
    unsigned e = gid >> 4;          // grid sized exactly: e < NE always
    unsigned c = gid & 15;
    const int lane = threadIdx.x & 63;
    const int s = src[e];
    const int d = dst[e];
    int slot = 0;
    if (c == 0) {
        slot = atomicAdd(&cur[(d >> 5) * CPAD], 1);
        mdst[slot] = (unsigned char)(d & (BIN - 1));
    }
    slot = __shfl(slot, lane & 48, 64);   // broadcast from 16-group leader

    const float* xp  = x  + (size_t)s * D + c * 8;
    const float* eap = ea + (size_t)e * D + c * 8;
    float4 a0 = reinterpret_cast<const float4*>(xp)[0];
    float4 a1 = reinterpret_cast<const float4*>(xp)[1];
    float4 b0 = reinterpret_cast<const float4*>(eap)[0];
    float4 b1 = reinterpret_cast<const float4*>(eap)[1];
    float m[8] = {fmaxf(a0.x + b0.x, 0.0f), fmaxf(a0.y + b0.y, 0.0f),
                  fmaxf(a0.z + b0.z, 0.0f), fmaxf(a0.w + b0.w, 0.0f),
                  fmaxf(a1.x + b1.x, 0.0f), fmaxf(a1.y + b1.y, 0.0f),
                  fmaxf(a1.z + b1.z, 0.0f), fmaxf(a1.w + b1.w, 0.0f)};
    bf16x8 o = pack_bf8(m);
    *reinterpret_cast<bf16x8*>(mbuf + (size_t)slot * D + c * 8) = o;
}

// ---------------------------------------------------------------------------
// Pass B + MLP fused. Block = bin = 32 nodes. Init LDS G1 with (1+eps)x,
// stream the bin's message segment SEQUENTIALLY (16 B/lane, 4 msgs/wave/step),
// ds_add_f32 accumulate (order-free), then 2-layer MFMA MLP -> out.
// ---------------------------------------------------------------------------
__global__ __launch_bounds__(256) void k_fused2(const float* __restrict__ x,
                                                const unsigned short* __restrict__ mbuf,
                                                const unsigned char* __restrict__ mdst,
                                                const int* __restrict__ binoff,
                                                const float* __restrict__ eps,
                                                const short* __restrict__ W1h,
                                                const short* __restrict__ W1l,
                                                const short* __restrict__ W2h,
                                                const short* __restrict__ W2l,
                                                const float* __restrict__ b1,
                                                const float* __restrict__ b2,
                                                float* __restrict__ out) {
    __shared__ float G1[32 * LDG];  // 16.9 KB
    __shared__ float G2[32 * LDG];  // 16.9 KB

    const int wave = threadIdx.x >> 6;
    const int lane = threadIdx.x & 63;
    const int b = blockIdx.x;
    const int nb = b * BIN;

    // ---- init G1 = (1+eps) * x (rows nb..nb+31), vectorized ----
    {
        const float sc = 1.0f + eps[0];
        for (int i = threadIdx.x; i < 32 * 32; i += 256) {   // 32 rows x 32 float4
            int row = i >> 5, q = i & 31;
            float4 xx = reinterpret_cast<const float4*>(x)[(size_t)(nb + row) * 32 + q];
            float4 v;
            v.x = sc * xx.x; v.y = sc * xx.y; v.z = sc * xx.z; v.w = sc * xx.w;
            *reinterpret_cast<float4*>(&G1[row * LDG + q * 4]) = v;
        }
    }
    __syncthreads();

    // ---- accumulate bin messages (sequential stream, LDS f32 atomics) ----
    {
        const int j0 = binoff[b], j1 = binoff[b + 1];
        const int cc = lane & 15;        // 8-feature chunk
        const int half = lane >> 4;      // msg sub-index 0..3
        for (int m = j0 + wave * 4 + half; m < j1; m += 16) {
            int ld = mdst[m];
            u16x8 mv = *reinterpret_cast<const u16x8*>(mbuf + (size_t)m * D + cc * 8);
            float* ap = &G1[ld * LDG + cc * 8];
#pragma unroll
            for (int i = 0; i < 8; ++i)
                atomicAdd(ap + i, bf2f((short)mv[i]));
        }
    }
    __syncthreads();

    const int r = lane & 15;   // row within 16-tile / W col within 16-tile
    const int g = lane >> 4;   // k-group (8) / D-row group (4)

    // ---------------- layer 1 (3-term bf16 MFMA) ----------------
    {
        f32x4 acc[2][2];
#pragma unroll
        for (int mt = 0; mt < 2; ++mt)
#pragma unroll
            for (int nl = 0; nl < 2; ++nl) {
                acc[mt][nl].x = 0.f; acc[mt][nl].y = 0.f;
                acc[mt][nl].z = 0.f; acc[mt][nl].w = 0.f;
            }

#pragma unroll
        for (int kc = 0; kc < 4; ++kc) {
            const int k0 = kc * 32;
            bf16x8 ahi[2], alo[2];
#pragma unroll
            for (int mt = 0; mt < 2; ++mt) {
                const float* gp = &G1[(mt * 16 + r) * LDG + k0 + g * 8];
                float vals[8];
                *reinterpret_cast<float4*>(&vals[0]) = reinterpret_cast<const float4*>(gp)[0];
                *reinterpret_cast<float4*>(&vals[4]) = reinterpret_cast<const float4*>(gp)[1];
                pack_hilo(vals, ahi[mt], alo[mt]);
            }
#pragma unroll
            for (int nl = 0; nl < 2; ++nl) {
                const int nt = wave * 2 + nl;
                const int wb = (nt * 16 + r) * D + k0 + g * 8;
                bf16x8 whi = *reinterpret_cast<const bf16x8*>(&W1h[wb]);
                bf16x8 wlo = *reinterpret_cast<const bf16x8*>(&W1l[wb]);
#pragma unroll
                for (int mt = 0; mt < 2; ++mt) {
                    acc[mt][nl] = __builtin_amdgcn_mfma_f32_16x16x32_bf16(ahi[mt], whi, acc[mt][nl], 0, 0, 0);
                    acc[mt][nl] = __builtin_amdgcn_mfma_f32_16x16x32_bf16(ahi[mt], wlo, acc[mt][nl], 0, 0, 0);
                    acc[mt][nl] = __builtin_amdgcn_mfma_f32_16x16x32_bf16(alo[mt], whi, acc[mt][nl], 0, 0, 0);
                }
            }
        }

#pragma unroll
        for (int nl = 0; nl < 2; ++nl) {
            const int col = (wave * 2 + nl) * 16 + r;
            const float bb = b1[col];
#pragma unroll
            for (int mt = 0; mt < 2; ++mt)
#pragma unroll
                for (int q = 0; q < 4; ++q)
                    G2[(mt * 16 + g * 4 + q) * LDG + col] = fmaxf(acc[mt][nl][q] + bb, 0.0f);
        }
    }
    __syncthreads();

    // ---------------- layer 2 (2-term, single-bf16 A) ----------------
    {
        f32x4 acc[2][2];
#pragma unroll
        for (int mt = 0; mt < 2; ++mt)
#pragma unroll
            for (int nl = 0; nl < 2; ++nl) {
                acc[mt][nl].x = 0.f; acc[mt][nl].y = 0.f;
                acc[mt][nl].z = 0.f; acc[mt][nl].w = 0.f;
            }

#pragma unroll
        for (int kc = 0; kc < 4; ++kc) {
            const int k0 = kc * 32;
            bf16x8 a[2];
#pragma unroll
            for (int mt = 0; mt < 2; ++mt) {
                const float* gp = &G2[(mt * 16 + r) * LDG + k0 + g * 8];
                float vals[8];
                *reinterpret_cast<float4*>(&vals[0]) = reinterpret_cast<const float4*>(gp)[0];
                *reinterpret_cast<float4*>(&vals[4]) = reinterpret_cast<const float4*>(gp)[1];
                a[mt] = pack_bf8(vals);
            }
#pragma unroll
            for (int nl = 0; nl < 2; ++nl) {
                const int nt = wave * 2 + nl;
                const int wb = (nt * 16 + r) * D + k0 + g * 8;
                bf16x8 whi = *reinterpret_cast<const bf16x8*>(&W2h[wb]);
                bf16x8 wlo = *reinterpret_cast<const bf16x8*>(&W2l[wb]);
#pragma unroll
                for (int mt = 0; mt < 2; ++mt) {
                    acc[mt][nl] = __builtin_amdgcn_mfma_f32_16x16x32_bf16(a[mt], whi, acc[mt][nl], 0, 0, 0);
                    acc[mt][nl] = __builtin_amdgcn_mfma_f32_16x16x32_bf16(a[mt], wlo, acc[mt][nl], 0, 0, 0);
                }
            }
        }

#pragma unroll
        for (int nl = 0; nl < 2; ++nl) {
            const int col = (wave * 2 + nl) * 16 + r;
            const float bb = b2[col];
#pragma unroll
            for (int mt = 0; mt < 2; ++mt)
#pragma unroll
                for (int q = 0; q < 4; ++q) {
                    long row = nb + mt * 16 + g * 4 + q;
                    out[row * D + col] = acc[mt][nl][q] + bb;
                }
        }
    }
}

// ---------------------------------------------------------------------------
extern "C" void kernel_launch(void* const* d_in, const int* in_sizes, int n_in,
                              void* d_out, int out_size, void* d_ws, size_t ws_size,
                              hipStream_t stream) {
    const float* x   = (const float*)d_in[0];
    const int*   ei  = (const int*)d_in[1];   // int32 [2, NE]
    const float* ea  = (const float*)d_in[2];
    const float* eps = (const float*)d_in[3];
    const float* W1  = (const float*)d_in[4];
    const float* b1  = (const float*)d_in[5];
    const float* W2  = (const float*)d_in[6];
    const float* b2  = (const float*)d_in[7];
    float* out = (float*)d_out;

    const int* src = ei;
    const int* dst = ei + NE;

    // ws layout
    int* part   = (int*)d_ws;                      // NHB*KB2 = 200000 ints
    int* binoff = part + NHB * KB2;                // KB2+1
    int* cur    = binoff + KB2 + 1;                // KB2*CPAD = 100000 ints
    unsigned char* mdst = (unsigned char*)(cur + KB2 * CPAD);  // NE bytes
    size_t hdr_bytes = (size_t)(NHB * KB2 + KB2 + 1 + KB2 * CPAD) * 4 + NE;
    size_t mb_off = (hdr_bytes + 255) & ~(size_t)255;
    unsigned short* mbuf = (unsigned short*)((char*)d_ws + mb_off);  // NE*D bf16 = 164 MB
    short* wsp = (short*)(mbuf + (size_t)NE * D);
    short* W1h = wsp;
    short* W1l = W1h + D * D;
    short* W2h = W1l + D * D;
    short* W2l = W2h + D * D;

    k_wsplit<<<32,  256, 0, stream>>>(W1, W1h, W1l);
    k_wsplit<<<32,  256, 0, stream>>>(W2, W2h, W2l);
    k_phist <<<NHB, 256, 0, stream>>>(dst, part);
    k_bscan <<<1,  1024, 0, stream>>>(part, binoff, cur);

    // Pass A: edge-order streaming, padded-counter binned append
    k_msg<<<NE * 16 / 256, 256, 0, stream>>>(x, src, dst, ea, cur, mdst, mbuf);
    // Pass B + MLP: bin-order sequential accumulate + MFMA -> out
    k_fused2<<<KB2, 256, 0, stream>>>(x, mbuf, mdst, binoff, eps,
                                      W1h, W1l, W2h, W2l, b1, b2, out);
}

// Round 9
// 306.583 us; speedup vs baseline: 2.1550x; 2.1550x over previous
//
#include <hip/hip_runtime.h>
#include <hip/hip_bf16.h>

constexpr int NN = 100000;
constexpr int NE = 640000;
constexpr int D  = 128;
constexpr int NB = (NN + 255) / 256;  // 391

typedef __attribute__((ext_vector_type(8))) short bf16x8;
typedef __attribute__((ext_vector_type(4))) float f32x4;

__device__ __forceinline__ short f2bf(float f) {
    union { float f; unsigned u; } v; v.f = f;
    unsigned r = v.u + 0x7FFF + ((v.u >> 16) & 1);
    return (short)(r >> 16);
}
__device__ __forceinline__ float bf2f(short h) {
    union { unsigned u; float f; } v;
    v.u = ((unsigned)(unsigned short)h) << 16;
    return v.f;
}
__device__ __forceinline__ unsigned cvtpk(float a, float b) {
    union { __hip_bfloat162 h2; unsigned u; } cv;
    float2 f; f.x = a; f.y = b;
    cv.h2 = __float22bfloat162_rn(f);
    return cv.u;
}
__device__ __forceinline__ void pack_hilo(const float* v, bf16x8& hi, bf16x8& lo) {
#pragma unroll
    for (int i = 0; i < 4; ++i) {
        unsigned u = cvtpk(v[2 * i], v[2 * i + 1]);
        short h0 = (short)(u & 0xFFFF), h1 = (short)(u >> 16);
        hi[2 * i] = h0; hi[2 * i + 1] = h1;
        unsigned ul = cvtpk(v[2 * i] - bf2f(h0), v[2 * i + 1] - bf2f(h1));
        lo[2 * i] = (short)(ul & 0xFFFF); lo[2 * i + 1] = (short)(ul >> 16);
    }
}
__device__ __forceinline__ bf16x8 pack_bf8(const float* v) {
    bf16x8 o;
#pragma unroll
    for (int i = 0; i < 4; ++i) {
        unsigned u = cvtpk(v[2 * i], v[2 * i + 1]);
        o[2 * i] = (short)(u & 0xFFFF); o[2 * i + 1] = (short)(u >> 16);
    }
    return o;
}

// ---------------------------------------------------------------------------
// Counting sort of edges by dst (proven chain, unchanged since r7)
// ---------------------------------------------------------------------------
__global__ __launch_bounds__(256) void k_zero(int* __restrict__ cnt) {
    int i = blockIdx.x * 256 + threadIdx.x;
    if (i < NN) cnt[i] = 0;
}

__global__ __launch_bounds__(256) void k_hist(const int* __restrict__ dst,
                                              int* __restrict__ cnt) {
    int e = blockIdx.x * 256 + threadIdx.x;
    if (e < NE) atomicAdd(&cnt[dst[e]], 1);
}

__global__ __launch_bounds__(256) void k_bsum(const int* __restrict__ cnt,
                                              int* __restrict__ bsum) {
    int i = blockIdx.x * 256 + threadIdx.x;
    int v = (i < NN) ? cnt[i] : 0;
#pragma unroll
    for (int s = 32; s; s >>= 1) v += __shfl_down(v, s, 64);
    __shared__ int w[4];
    if ((threadIdx.x & 63) == 0) w[threadIdx.x >> 6] = v;
    __syncthreads();
    if (threadIdx.x == 0) bsum[blockIdx.x] = w[0] + w[1] + w[2] + w[3];
}

__global__ __launch_bounds__(512) void k_scan_bsum(const int* __restrict__ bsum,
                                                   int* __restrict__ bboff) {
    int t = threadIdx.x, lane = t & 63;
    int v = (t < NB) ? bsum[t] : 0;
    int incl = v;
#pragma unroll
    for (int s = 1; s < 64; s <<= 1) {
        int u = __shfl_up(incl, s, 64);
        if (lane >= s) incl += u;
    }
    __shared__ int wt[8], wp[8];
    if (lane == 63) wt[t >> 6] = incl;
    __syncthreads();
    if (t == 0) { int run = 0; for (int i = 0; i < 8; ++i) { wp[i] = run; run += wt[i]; } }
    __syncthreads();
    if (t < NB) bboff[t] = incl - v + wp[t >> 6];
}

__global__ __launch_bounds__(256) void k_scan_final(const int* __restrict__ cnt,
                                                    const int* __restrict__ bboff,
                                                    int* __restrict__ off,
                                                    int* __restrict__ cur) {
    int b = blockIdx.x, t = threadIdx.x, lane = t & 63;
    int i = b * 256 + t;
    int v = (i < NN) ? cnt[i] : 0;
    int incl = v;
#pragma unroll
    for (int s = 1; s < 64; s <<= 1) {
        int u = __shfl_up(incl, s, 64);
        if (lane >= s) incl += u;
    }
    __shared__ int wt[4], wp[4];
    if (lane == 63) wt[t >> 6] = incl;
    __syncthreads();
    if (t == 0) { int run = 0; for (int q = 0; q < 4; ++q) { wp[q] = run; run += wt[q]; } }
    __syncthreads();
    int excl = incl - v + wp[t >> 6] + bboff[b];
    if (i < NN) { off[i] = excl; cur[i] = excl; }
    if (i == 0) off[NN] = NE;
}

__global__ __launch_bounds__(256) void k_perm(const int* __restrict__ dst,
                                              const int* __restrict__ src,
                                              int* __restrict__ cur,
                                              int2* __restrict__ ps) {
    int e = blockIdx.x * 256 + threadIdx.x;
    if (e < NE) {
        int p = atomicAdd(&cur[dst[e]], 1);
        int2 v; v.x = e; v.y = src[e];
        ps[p] = v;
    }
}

// ---------------------------------------------------------------------------
// W pre-split: W[k][n] f32 -> Wt_hi[n][k], Wt_lo[n][k] bf16
// ---------------------------------------------------------------------------
__global__ __launch_bounds__(256) void k_wsplit(const float* __restrict__ W,
                                                short* __restrict__ Whi,
                                                short* __restrict__ Wlo) {
    for (int idx = blockIdx.x * 256 + threadIdx.x; idx < D * D; idx += gridDim.x * 256) {
        int n = idx >> 7, k = idx & 127;
        float w = W[k * D + n];
        short hi = f2bf(w);
        Whi[idx] = hi;
        Wlo[idx] = f2bf(w - bf2f(hi));
    }
}

// ---------------------------------------------------------------------------
// Fused aggregation + 2-layer MLP, BIN=16 nodes/block for 8 blocks/CU.
//   phase 1: wave w gathers+aggregates nodes [nb+4w, nb+4w+4) -> LDS G1
//   phase 2a: layer 1 (A=G1 hi/lo x W1 hi/lo, 3-term MFMA) -> relu -> G2
//   phase 2b: layer 2 (A=G2 single-bf16 x W2 hi/lo, 2-term) -> out
// Single 16-row m-tile; 4 waves split N as 4 x 32 cols (nl=2).
// LDS rows padded to 132 floats (2-way-max conflicts on ds_read_b128).
// __launch_bounds__(256,8): cap 64 VGPR -> 8 blocks/CU (LDS 16.9 KB).
// ---------------------------------------------------------------------------
constexpr int LDG = 132;

__global__ __launch_bounds__(256, 8) void k_fused(const float* __restrict__ x,
                                                  const float* __restrict__ ea,
                                                  const int* __restrict__ off,
                                                  const int2* __restrict__ ps,
                                                  const float* __restrict__ eps,
                                                  const short* __restrict__ W1h,
                                                  const short* __restrict__ W1l,
                                                  const short* __restrict__ W2h,
                                                  const short* __restrict__ W2l,
                                                  const float* __restrict__ b1,
                                                  const float* __restrict__ b2,
                                                  float* __restrict__ out) {
    __shared__ float G1[16 * LDG];  // 8.45 KB
    __shared__ float G2[16 * LDG];  // 8.45 KB

    const int wave = threadIdx.x >> 6;
    const int lane = threadIdx.x & 63;
    const int nb = blockIdx.x * 16;

    // ---------------- phase 1: gather-aggregate 4 nodes per wave ----------
    {
        const int lo2 = lane * 2;
        const float sc = 1.0f + eps[0];
        for (int t = 0; t < 4; ++t) {
            const int n = nb + wave * 4 + t;
            const int j0 = off[n], j1 = off[n + 1];
            float accx = 0.0f, accy = 0.0f;
            for (int j = j0; j < j1; j += 8) {
                int ee[8], ss[8];
#pragma unroll
                for (int q = 0; q < 8; ++q) {
                    int jj = j + q; jj = (jj < j1) ? jj : (j1 - 1);
                    int2 p = ps[jj];
                    ee[q] = p.x; ss[q] = p.y;
                }
                float2 xa[8], eb[8];
#pragma unroll
                for (int q = 0; q < 8; ++q) {
                    xa[q] = *reinterpret_cast<const float2*>(x  + (size_t)ss[q] * D + lo2);
                    eb[q] = *reinterpret_cast<const float2*>(ea + (size_t)ee[q] * D + lo2);
                }
#pragma unroll
                for (int q = 0; q < 8; ++q) {
                    float mx = fmaxf(xa[q].x + eb[q].x, 0.0f);
                    float my = fmaxf(xa[q].y + eb[q].y, 0.0f);
                    bool ok = (j + q) < j1;
                    accx += ok ? mx : 0.0f;
                    accy += ok ? my : 0.0f;
                }
            }
            float2 xx = *reinterpret_cast<const float2*>(x + (size_t)n * D + lo2);
            float2 o;
            o.x = fmaf(sc, xx.x, accx);
            o.y = fmaf(sc, xx.y, accy);
            *reinterpret_cast<float2*>(&G1[(wave * 4 + t) * LDG + lo2]) = o;
        }
    }
    __syncthreads();

    const int r = lane & 15;   // A-row / W-col within 16-tile
    const int g = lane >> 4;   // k-group (8 k) / D-row group (4 rows)

    // ---------------- phase 2a: layer 1 (3-term bf16 MFMA) ----------------
    {
        f32x4 acc[2];
#pragma unroll
        for (int nl = 0; nl < 2; ++nl) {
            acc[nl].x = 0.f; acc[nl].y = 0.f; acc[nl].z = 0.f; acc[nl].w = 0.f;
        }

#pragma unroll
        for (int kc = 0; kc < 4; ++kc) {
            const int k0 = kc * 32;
            bf16x8 ahi, alo;
            {
                const float* gp = &G1[r * LDG + k0 + g * 8];
                float vals[8];
                *reinterpret_cast<float4*>(&vals[0]) = reinterpret_cast<const float4*>(gp)[0];
                *reinterpret_cast<float4*>(&vals[4]) = reinterpret_cast<const float4*>(gp)[1];
                pack_hilo(vals, ahi, alo);
            }
#pragma unroll
            for (int nl = 0; nl < 2; ++nl) {
                const int nt = wave * 2 + nl;
                const int wb = (nt * 16 + r) * D + k0 + g * 8;
                bf16x8 whi = *reinterpret_cast<const bf16x8*>(&W1h[wb]);
                bf16x8 wlo = *reinterpret_cast<const bf16x8*>(&W1l[wb]);
                acc[nl] = __builtin_amdgcn_mfma_f32_16x16x32_bf16(ahi, whi, acc[nl], 0, 0, 0);
                acc[nl] = __builtin_amdgcn_mfma_f32_16x16x32_bf16(ahi, wlo, acc[nl], 0, 0, 0);
                acc[nl] = __builtin_amdgcn_mfma_f32_16x16x32_bf16(alo, whi, acc[nl], 0, 0, 0);
            }
        }

        // epilogue: bias + relu -> G2 (row = g*4+q, col = nt*16+r)
#pragma unroll
        for (int nl = 0; nl < 2; ++nl) {
            const int col = (wave * 2 + nl) * 16 + r;
            const float bb = b1[col];
#pragma unroll
            for (int q = 0; q < 4; ++q)
                G2[(g * 4 + q) * LDG + col] = fmaxf(acc[nl][q] + bb, 0.0f);
        }
    }
    __syncthreads();

    // ---------------- phase 2b: layer 2 (2-term, single-bf16 A) -----------
    {
        f32x4 acc[2];
#pragma unroll
        for (int nl = 0; nl < 2; ++nl) {
            acc[nl].x = 0.f; acc[nl].y = 0.f; acc[nl].z = 0.f; acc[nl].w = 0.f;
        }

#pragma unroll
        for (int kc = 0; kc < 4; ++kc) {
            const int k0 = kc * 32;
            bf16x8 a;
            {
                const float* gp = &G2[r * LDG + k0 + g * 8];
                float vals[8];
                *reinterpret_cast<float4*>(&vals[0]) = reinterpret_cast<const float4*>(gp)[0];
                *reinterpret_cast<float4*>(&vals[4]) = reinterpret_cast<const float4*>(gp)[1];
                a = pack_bf8(vals);
            }
#pragma unroll
            for (int nl = 0; nl < 2; ++nl) {
                const int nt = wave * 2 + nl;
                const int wb = (nt * 16 + r) * D + k0 + g * 8;
                bf16x8 whi = *reinterpret_cast<const bf16x8*>(&W2h[wb]);
                bf16x8 wlo = *reinterpret_cast<const bf16x8*>(&W2l[wb]);
                acc[nl] = __builtin_amdgcn_mfma_f32_16x16x32_bf16(a, whi, acc[nl], 0, 0, 0);
                acc[nl] = __builtin_amdgcn_mfma_f32_16x16x32_bf16(a, wlo, acc[nl], 0, 0, 0);
            }
        }

#pragma unroll
        for (int nl = 0; nl < 2; ++nl) {
            const int col = (wave * 2 + nl) * 16 + r;
            const float bb = b2[col];
#pragma unroll
            for (int q = 0; q < 4; ++q) {
                long row = nb + g * 4 + q;
                out[row * D + col] = acc[nl][q] + bb;
            }
        }
    }
}

// ---------------------------------------------------------------------------
extern "C" void kernel_launch(void* const* d_in, const int* in_sizes, int n_in,
                              void* d_out, int out_size, void* d_ws, size_t ws_size,
                              hipStream_t stream) {
    const float* x   = (const float*)d_in[0];
    const int*   ei  = (const int*)d_in[1];   // int32 [2, NE]
    const float* ea  = (const float*)d_in[2];
    const float* eps = (const float*)d_in[3];
    const float* W1  = (const float*)d_in[4];
    const float* b1  = (const float*)d_in[5];
    const float* W2  = (const float*)d_in[6];
    const float* b2  = (const float*)d_in[7];
    float* out = (float*)d_out;

    const int* src = ei;
    const int* dst = ei + NE;

    // ws layout (~6.5 MB)
    int* base  = (int*)d_ws;
    int* cnt   = base;                 // NN
    int* off   = cnt + NN;             // NN+1
    int* cur   = off + NN + 1;         // NN
    int* bsum  = cur + NN;             // NB
    int* bboff = bsum + NB;            // NB
    size_t ps_off = ((size_t)(3 * NN + 1 + 2 * NB) + 1) & ~(size_t)1;
    int2* ps   = (int2*)(base + ps_off);               // NE int2
    short* wsp = (short*)(base + ps_off + 2 * (size_t)NE);
    short* W1h = wsp;                  // D*D each
    short* W1l = W1h + D * D;
    short* W2h = W1l + D * D;
    short* W2l = W2h + D * D;

    k_wsplit    <<<32,               256, 0, stream>>>(W1, W1h, W1l);
    k_wsplit    <<<32,               256, 0, stream>>>(W2, W2h, W2l);
    k_zero      <<<NB,               256, 0, stream>>>(cnt);
    k_hist      <<<(NE + 255) / 256, 256, 0, stream>>>(dst, cnt);
    k_bsum      <<<NB,               256, 0, stream>>>(cnt, bsum);
    k_scan_bsum <<<1,                512, 0, stream>>>(bsum, bboff);
    k_scan_final<<<NB,               256, 0, stream>>>(cnt, bboff, off, cur);
    k_perm      <<<(NE + 255) / 256, 256, 0, stream>>>(dst, src, cur, ps);

    // fused: gather-aggregate -> LDS -> 2-layer MFMA MLP -> out (16 nodes/blk)
    k_fused<<<NN / 16, 256, 0, stream>>>(x, ea, off, ps, eps,
                                         W1h, W1l, W2h, W2l, b1, b2, out);
}

// Round 10
// 273.365 us; speedup vs baseline: 2.4169x; 1.1215x over previous
//
#include <hip/hip_runtime.h>
#include <hip/hip_bf16.h>

constexpr int NN = 100000;
constexpr int NE = 640000;
constexpr int D  = 128;
constexpr int NB = (NN + 255) / 256;  // 391

typedef __attribute__((ext_vector_type(8))) short bf16x8;
typedef __attribute__((ext_vector_type(4))) float f32x4;

__device__ __forceinline__ short f2bf(float f) {
    union { float f; unsigned u; } v; v.f = f;
    unsigned r = v.u + 0x7FFF + ((v.u >> 16) & 1);
    return (short)(r >> 16);
}
__device__ __forceinline__ float bf2f(short h) {
    union { unsigned u; float f; } v;
    v.u = ((unsigned)(unsigned short)h) << 16;
    return v.f;
}
__device__ __forceinline__ unsigned cvtpk(float a, float b) {
    union { __hip_bfloat162 h2; unsigned u; } cv;
    float2 f; f.x = a; f.y = b;
    cv.h2 = __float22bfloat162_rn(f);
    return cv.u;
}
__device__ __forceinline__ void pack_hilo(const float* v, bf16x8& hi, bf16x8& lo) {
#pragma unroll
    for (int i = 0; i < 4; ++i) {
        unsigned u = cvtpk(v[2 * i], v[2 * i + 1]);
        short h0 = (short)(u & 0xFFFF), h1 = (short)(u >> 16);
        hi[2 * i] = h0; hi[2 * i + 1] = h1;
        unsigned ul = cvtpk(v[2 * i] - bf2f(h0), v[2 * i + 1] - bf2f(h1));
        lo[2 * i] = (short)(ul & 0xFFFF); lo[2 * i + 1] = (short)(ul >> 16);
    }
}
__device__ __forceinline__ bf16x8 pack_bf8(const float* v) {
    bf16x8 o;
#pragma unroll
    for (int i = 0; i < 4; ++i) {
        unsigned u = cvtpk(v[2 * i], v[2 * i + 1]);
        o[2 * i] = (short)(u & 0xFFFF); o[2 * i + 1] = (short)(u >> 16);
    }
    return o;
}

// ---------------------------------------------------------------------------
// Counting sort of edges by dst (proven chain, unchanged since r7)
// ---------------------------------------------------------------------------
__global__ __launch_bounds__(256) void k_zero(int* __restrict__ cnt) {
    int i = blockIdx.x * 256 + threadIdx.x;
    if (i < NN) cnt[i] = 0;
}

__global__ __launch_bounds__(256) void k_hist(const int* __restrict__ dst,
                                              int* __restrict__ cnt) {
    int e = blockIdx.x * 256 + threadIdx.x;
    if (e < NE) atomicAdd(&cnt[dst[e]], 1);
}

__global__ __launch_bounds__(256) void k_bsum(const int* __restrict__ cnt,
                                              int* __restrict__ bsum) {
    int i = blockIdx.x * 256 + threadIdx.x;
    int v = (i < NN) ? cnt[i] : 0;
#pragma unroll
    for (int s = 32; s; s >>= 1) v += __shfl_down(v, s, 64);
    __shared__ int w[4];
    if ((threadIdx.x & 63) == 0) w[threadIdx.x >> 6] = v;
    __syncthreads();
    if (threadIdx.x == 0) bsum[blockIdx.x] = w[0] + w[1] + w[2] + w[3];
}

__global__ __launch_bounds__(512) void k_scan_bsum(const int* __restrict__ bsum,
                                                   int* __restrict__ bboff) {
    int t = threadIdx.x, lane = t & 63;
    int v = (t < NB) ? bsum[t] : 0;
    int incl = v;
#pragma unroll
    for (int s = 1; s < 64; s <<= 1) {
        int u = __shfl_up(incl, s, 64);
        if (lane >= s) incl += u;
    }
    __shared__ int wt[8], wp[8];
    if (lane == 63) wt[t >> 6] = incl;
    __syncthreads();
    if (t == 0) { int run = 0; for (int i = 0; i < 8; ++i) { wp[i] = run; run += wt[i]; } }
    __syncthreads();
    if (t < NB) bboff[t] = incl - v + wp[t >> 6];
}

__global__ __launch_bounds__(256) void k_scan_final(const int* __restrict__ cnt,
                                                    const int* __restrict__ bboff,
                                                    int* __restrict__ off,
                                                    int* __restrict__ cur) {
    int b = blockIdx.x, t = threadIdx.x, lane = t & 63;
    int i = b * 256 + t;
    int v = (i < NN) ? cnt[i] : 0;
    int incl = v;
#pragma unroll
    for (int s = 1; s < 64; s <<= 1) {
        int u = __shfl_up(incl, s, 64);
        if (lane >= s) incl += u;
    }
    __shared__ int wt[4], wp[4];
    if (lane == 63) wt[t >> 6] = incl;
    __syncthreads();
    if (t == 0) { int run = 0; for (int q = 0; q < 4; ++q) { wp[q] = run; run += wt[q]; } }
    __syncthreads();
    int excl = incl - v + wp[t >> 6] + bboff[b];
    if (i < NN) { off[i] = excl; cur[i] = excl; }
    if (i == 0) off[NN] = NE;
}

__global__ __launch_bounds__(256) void k_perm(const int* __restrict__ dst,
                                              const int* __restrict__ src,
                                              int* __restrict__ cur,
                                              int2* __restrict__ ps) {
    int e = blockIdx.x * 256 + threadIdx.x;
    if (e < NE) {
        int p = atomicAdd(&cur[dst[e]], 1);
        int2 v; v.x = e; v.y = src[e];
        ps[p] = v;
    }
}

// ---------------------------------------------------------------------------
// W pre-split: W[k][n] f32 -> Wt_hi[n][k], Wt_lo[n][k] bf16
// ---------------------------------------------------------------------------
__global__ __launch_bounds__(256) void k_wsplit(const float* __restrict__ W,
                                                short* __restrict__ Whi,
                                                short* __restrict__ Wlo) {
    for (int idx = blockIdx.x * 256 + threadIdx.x; idx < D * D; idx += gridDim.x * 256) {
        int n = idx >> 7, k = idx & 127;
        float w = W[k * D + n];
        short hi = f2bf(w);
        Whi[idx] = hi;
        Wlo[idx] = f2bf(w - bf2f(hi));
    }
}

// ---------------------------------------------------------------------------
// Fused aggregation + 2-layer MLP (r7 geometry: 32 nodes/block, 4 blocks/CU).
// Phase 1 processes NODE PAIRS with merged 16-edge batches -> 32 data loads
// in flight per wave per step (2x r7's depth). __launch_bounds__(256,4)
// gives the compiler a 128-VGPR budget at unchanged occupancy (LDS-capped).
// ---------------------------------------------------------------------------
constexpr int LDG = 132;  // padded LDS row stride (floats)

__global__ __launch_bounds__(256, 4) void k_fused(const float* __restrict__ x,
                                                  const float* __restrict__ ea,
                                                  const int* __restrict__ off,
                                                  const int2* __restrict__ ps,
                                                  const float* __restrict__ eps,
                                                  const short* __restrict__ W1h,
                                                  const short* __restrict__ W1l,
                                                  const short* __restrict__ W2h,
                                                  const short* __restrict__ W2l,
                                                  const float* __restrict__ b1,
                                                  const float* __restrict__ b2,
                                                  float* __restrict__ out) {
    __shared__ float G1[32 * LDG];  // 16.9 KB
    __shared__ float G2[32 * LDG];  // 16.9 KB

    const int wave = threadIdx.x >> 6;
    const int lane = threadIdx.x & 63;
    const int nb = blockIdx.x * 32;

    // ---------------- phase 1: gather-aggregate, 4 node-pairs per wave ----
    {
        const int lo2 = lane * 2;
        const float sc = 1.0f + eps[0];
        for (int t = 0; t < 4; ++t) {
            const int n0 = nb + wave * 8 + 2 * t;
            const int j0a = off[n0],     j1a = off[n0 + 1];
            const int j0b = j1a;
            const int j1b = off[n0 + 2];
            float axA = 0.0f, ayA = 0.0f, axB = 0.0f, ayB = 0.0f;
            const int itA = (j1a - j0a + 7) >> 3;
            const int itB = (j1b - j0b + 7) >> 3;
            const int iters = (itA > itB) ? itA : itB;
            for (int i = 0; i < iters; ++i) {
                int eeA[8], ssA[8], eeB[8], ssB[8];
#pragma unroll
                for (int q = 0; q < 8; ++q) {
                    int ja = j0a + i * 8 + q; ja = (ja < j1a) ? ja : (j1a - 1); ja = (ja > 0) ? ja : 0;
                    int2 pa = ps[ja]; eeA[q] = pa.x; ssA[q] = pa.y;
                    int jb = j0b + i * 8 + q; jb = (jb < j1b) ? jb : (j1b - 1); jb = (jb > 0) ? jb : 0;
                    int2 pb = ps[jb]; eeB[q] = pb.x; ssB[q] = pb.y;
                }
                float2 xaA[8], ebA[8], xaB[8], ebB[8];
#pragma unroll
                for (int q = 0; q < 8; ++q) {
                    xaA[q] = *reinterpret_cast<const float2*>(x  + (size_t)ssA[q] * D + lo2);
                    ebA[q] = *reinterpret_cast<const float2*>(ea + (size_t)eeA[q] * D + lo2);
                    xaB[q] = *reinterpret_cast<const float2*>(x  + (size_t)ssB[q] * D + lo2);
                    ebB[q] = *reinterpret_cast<const float2*>(ea + (size_t)eeB[q] * D + lo2);
                }
#pragma unroll
                for (int q = 0; q < 8; ++q) {
                    bool okA = (j0a + i * 8 + q) < j1a;
                    bool okB = (j0b + i * 8 + q) < j1b;
                    float mxA = fmaxf(xaA[q].x + ebA[q].x, 0.0f);
                    float myA = fmaxf(xaA[q].y + ebA[q].y, 0.0f);
                    axA += okA ? mxA : 0.0f;
                    ayA += okA ? myA : 0.0f;
                    float mxB = fmaxf(xaB[q].x + ebB[q].x, 0.0f);
                    float myB = fmaxf(xaB[q].y + ebB[q].y, 0.0f);
                    axB += okB ? mxB : 0.0f;
                    ayB += okB ? myB : 0.0f;
                }
            }
            float2 xxA = *reinterpret_cast<const float2*>(x + (size_t)n0 * D + lo2);
            float2 xxB = *reinterpret_cast<const float2*>(x + (size_t)(n0 + 1) * D + lo2);
            float2 oA, oB;
            oA.x = fmaf(sc, xxA.x, axA);
            oA.y = fmaf(sc, xxA.y, ayA);
            oB.x = fmaf(sc, xxB.x, axB);
            oB.y = fmaf(sc, xxB.y, ayB);
            *reinterpret_cast<float2*>(&G1[(wave * 8 + 2 * t)     * LDG + lo2]) = oA;
            *reinterpret_cast<float2*>(&G1[(wave * 8 + 2 * t + 1) * LDG + lo2]) = oB;
        }
    }
    __syncthreads();

    const int r = lane & 15;   // A-row / W-col within 16-tile
    const int g = lane >> 4;   // k-group (8 k) / D-row group (4 rows)

    // ---------------- phase 2a: layer 1 (3-term bf16 MFMA) ----------------
    {
        f32x4 acc[2][2];
#pragma unroll
        for (int mt = 0; mt < 2; ++mt)
#pragma unroll
            for (int nl = 0; nl < 2; ++nl) {
                acc[mt][nl].x = 0.f; acc[mt][nl].y = 0.f;
                acc[mt][nl].z = 0.f; acc[mt][nl].w = 0.f;
            }

#pragma unroll
        for (int kc = 0; kc < 4; ++kc) {
            const int k0 = kc * 32;
            bf16x8 ahi[2], alo[2];
#pragma unroll
            for (int mt = 0; mt < 2; ++mt) {
                const float* gp = &G1[(mt * 16 + r) * LDG + k0 + g * 8];
                float vals[8];
                *reinterpret_cast<float4*>(&vals[0]) = reinterpret_cast<const float4*>(gp)[0];
                *reinterpret_cast<float4*>(&vals[4]) = reinterpret_cast<const float4*>(gp)[1];
                pack_hilo(vals, ahi[mt], alo[mt]);
            }
#pragma unroll
            for (int nl = 0; nl < 2; ++nl) {
                const int nt = wave * 2 + nl;
                const int wb = (nt * 16 + r) * D + k0 + g * 8;
                bf16x8 whi = *reinterpret_cast<const bf16x8*>(&W1h[wb]);
                bf16x8 wlo = *reinterpret_cast<const bf16x8*>(&W1l[wb]);
#pragma unroll
                for (int mt = 0; mt < 2; ++mt) {
                    acc[mt][nl] = __builtin_amdgcn_mfma_f32_16x16x32_bf16(ahi[mt], whi, acc[mt][nl], 0, 0, 0);
                    acc[mt][nl] = __builtin_amdgcn_mfma_f32_16x16x32_bf16(ahi[mt], wlo, acc[mt][nl], 0, 0, 0);
                    acc[mt][nl] = __builtin_amdgcn_mfma_f32_16x16x32_bf16(alo[mt], whi, acc[mt][nl], 0, 0, 0);
                }
            }
        }

        // epilogue: bias + relu -> G2 (row = mt*16 + g*4 + q, col = nt*16 + r)
#pragma unroll
        for (int nl = 0; nl < 2; ++nl) {
            const int col = (wave * 2 + nl) * 16 + r;
            const float bb = b1[col];
#pragma unroll
            for (int mt = 0; mt < 2; ++mt)
#pragma unroll
                for (int q = 0; q < 4; ++q)
                    G2[(mt * 16 + g * 4 + q) * LDG + col] = fmaxf(acc[mt][nl][q] + bb, 0.0f);
        }
    }
    __syncthreads();

    // ---------------- phase 2b: layer 2 (2-term, single-bf16 A) -----------
    {
        f32x4 acc[2][2];
#pragma unroll
        for (int mt = 0; mt < 2; ++mt)
#pragma unroll
            for (int nl = 0; nl < 2; ++nl) {
                acc[mt][nl].x = 0.f; acc[mt][nl].y = 0.f;
                acc[mt][nl].z = 0.f; acc[mt][nl].w = 0.f;
            }

#pragma unroll
        for (int kc = 0; kc < 4; ++kc) {
            const int k0 = kc * 32;
            bf16x8 a[2];
#pragma unroll
            for (int mt = 0; mt < 2; ++mt) {
                const float* gp = &G2[(mt * 16 + r) * LDG + k0 + g * 8];
                float vals[8];
                *reinterpret_cast<float4*>(&vals[0]) = reinterpret_cast<const float4*>(gp)[0];
                *reinterpret_cast<float4*>(&vals[4]) = reinterpret_cast<const float4*>(gp)[1];
                a[mt] = pack_bf8(vals);
            }
#pragma unroll
            for (int nl = 0; nl < 2; ++nl) {
                const int nt = wave * 2 + nl;
                const int wb = (nt * 16 + r) * D + k0 + g * 8;
                bf16x8 whi = *reinterpret_cast<const bf16x8*>(&W2h[wb]);
                bf16x8 wlo = *reinterpret_cast<const bf16x8*>(&W2l[wb]);
#pragma unroll
                for (int mt = 0; mt < 2; ++mt) {
                    acc[mt][nl] = __builtin_amdgcn_mfma_f32_16x16x32_bf16(a[mt], whi, acc[mt][nl], 0, 0, 0);
                    acc[mt][nl] = __builtin_amdgcn_mfma_f32_16x16x32_bf16(a[mt], wlo, acc[mt][nl], 0, 0, 0);
                }
            }
        }

#pragma unroll
        for (int nl = 0; nl < 2; ++nl) {
            const int col = (wave * 2 + nl) * 16 + r;
            const float bb = b2[col];
#pragma unroll
            for (int mt = 0; mt < 2; ++mt)
#pragma unroll
                for (int q = 0; q < 4; ++q) {
                    long row = nb + mt * 16 + g * 4 + q;
                    out[row * D + col] = acc[mt][nl][q] + bb;
                }
        }
    }
}

// ---------------------------------------------------------------------------
extern "C" void kernel_launch(void* const* d_in, const int* in_sizes, int n_in,
                              void* d_out, int out_size, void* d_ws, size_t ws_size,
                              hipStream_t stream) {
    const float* x   = (const float*)d_in[0];
    const int*   ei  = (const int*)d_in[1];   // int32 [2, NE]
    const float* ea  = (const float*)d_in[2];
    const float* eps = (const float*)d_in[3];
    const float* W1  = (const float*)d_in[4];
    const float* b1  = (const float*)d_in[5];
    const float* W2  = (const float*)d_in[6];
    const float* b2  = (const float*)d_in[7];
    float* out = (float*)d_out;

    const int* src = ei;
    const int* dst = ei + NE;

    // ws layout (~6.5 MB)
    int* base  = (int*)d_ws;
    int* cnt   = base;                 // NN
    int* off   = cnt + NN;             // NN+1
    int* cur   = off + NN + 1;         // NN
    int* bsum  = cur + NN;             // NB
    int* bboff = bsum + NB;            // NB
    size_t ps_off = ((size_t)(3 * NN + 1 + 2 * NB) + 1) & ~(size_t)1;
    int2* ps   = (int2*)(base + ps_off);               // NE int2
    short* wsp = (short*)(base + ps_off + 2 * (size_t)NE);
    short* W1h = wsp;                  // D*D each
    short* W1l = W1h + D * D;
    short* W2h = W1l + D * D;
    short* W2l = W2h + D * D;

    k_wsplit    <<<32,               256, 0, stream>>>(W1, W1h, W1l);
    k_wsplit    <<<32,               256, 0, stream>>>(W2, W2h, W2l);
    k_zero      <<<NB,               256, 0, stream>>>(cnt);
    k_hist      <<<(NE + 255) / 256, 256, 0, stream>>>(dst, cnt);
    k_bsum      <<<NB,               256, 0, stream>>>(cnt, bsum);
    k_scan_bsum <<<1,                512, 0, stream>>>(bsum, bboff);
    k_scan_final<<<NB,               256, 0, stream>>>(cnt, bboff, off, cur);
    k_perm      <<<(NE + 255) / 256, 256, 0, stream>>>(dst, src, cur, ps);

    // fused: gather-aggregate (paired, 32-deep) -> LDS -> 2-layer MFMA MLP
    k_fused<<<NN / 32, 256, 0, stream>>>(x, ea, off, ps, eps,
                                         W1h, W1l, W2h, W2l, b1, b2, out);
}

// Round 11
// 266.449 us; speedup vs baseline: 2.4796x; 1.0260x over previous
//
#include <hip/hip_runtime.h>
#include <hip/hip_bf16.h>

constexpr int NN = 100000;
constexpr int NE = 640000;
constexpr int D  = 128;
constexpr int NB = (NN + 255) / 256;  // 391

typedef __attribute__((ext_vector_type(8))) short bf16x8;
typedef __attribute__((ext_vector_type(4))) float f32x4;

__device__ __forceinline__ short f2bf(float f) {
    union { float f; unsigned u; } v; v.f = f;
    unsigned r = v.u + 0x7FFF + ((v.u >> 16) & 1);
    return (short)(r >> 16);
}
__device__ __forceinline__ float bf2f(short h) {
    union { unsigned u; float f; } v;
    v.u = ((unsigned)(unsigned short)h) << 16;
    return v.f;
}
__device__ __forceinline__ unsigned cvtpk(float a, float b) {
    union { __hip_bfloat162 h2; unsigned u; } cv;
    float2 f; f.x = a; f.y = b;
    cv.h2 = __float22bfloat162_rn(f);
    return cv.u;
}

// ---------------------------------------------------------------------------
// Counting sort of edges by dst (proven chain, unchanged since r7)
// ---------------------------------------------------------------------------
__global__ __launch_bounds__(256) void k_zero(int* __restrict__ cnt) {
    int i = blockIdx.x * 256 + threadIdx.x;
    if (i < NN) cnt[i] = 0;
}

__global__ __launch_bounds__(256) void k_hist(const int* __restrict__ dst,
                                              int* __restrict__ cnt) {
    int e = blockIdx.x * 256 + threadIdx.x;
    if (e < NE) atomicAdd(&cnt[dst[e]], 1);
}

__global__ __launch_bounds__(256) void k_bsum(const int* __restrict__ cnt,
                                              int* __restrict__ bsum) {
    int i = blockIdx.x * 256 + threadIdx.x;
    int v = (i < NN) ? cnt[i] : 0;
#pragma unroll
    for (int s = 32; s; s >>= 1) v += __shfl_down(v, s, 64);
    __shared__ int w[4];
    if ((threadIdx.x & 63) == 0) w[threadIdx.x >> 6] = v;
    __syncthreads();
    if (threadIdx.x == 0) bsum[blockIdx.x] = w[0] + w[1] + w[2] + w[3];
}

__global__ __launch_bounds__(512) void k_scan_bsum(const int* __restrict__ bsum,
                                                   int* __restrict__ bboff) {
    int t = threadIdx.x, lane = t & 63;
    int v = (t < NB) ? bsum[t] : 0;
    int incl = v;
#pragma unroll
    for (int s = 1; s < 64; s <<= 1) {
        int u = __shfl_up(incl, s, 64);
        if (lane >= s) incl += u;
    }
    __shared__ int wt[8], wp[8];
    if (lane == 63) wt[t >> 6] = incl;
    __syncthreads();
    if (t == 0) { int run = 0; for (int i = 0; i < 8; ++i) { wp[i] = run; run += wt[i]; } }
    __syncthreads();
    if (t < NB) bboff[t] = incl - v + wp[t >> 6];
}

__global__ __launch_bounds__(256) void k_scan_final(const int* __restrict__ cnt,
                                                    const int* __restrict__ bboff,
                                                    int* __restrict__ off,
                                                    int* __restrict__ cur) {
    int b = blockIdx.x, t = threadIdx.x, lane = t & 63;
    int i = b * 256 + t;
    int v = (i < NN) ? cnt[i] : 0;
    int incl = v;
#pragma unroll
    for (int s = 1; s < 64; s <<= 1) {
        int u = __shfl_up(incl, s, 64);
        if (lane >= s) incl += u;
    }
    __shared__ int wt[4], wp[4];
    if (lane == 63) wt[t >> 6] = incl;
    __syncthreads();
    if (t == 0) { int run = 0; for (int q = 0; q < 4; ++q) { wp[q] = run; run += wt[q]; } }
    __syncthreads();
    int excl = incl - v + wp[t >> 6] + bboff[b];
    if (i < NN) { off[i] = excl; cur[i] = excl; }
    if (i == 0) off[NN] = NE;
}

__global__ __launch_bounds__(256) void k_perm(const int* __restrict__ dst,
                                              const int* __restrict__ src,
                                              int* __restrict__ cur,
                                              int2* __restrict__ ps) {
    int e = blockIdx.x * 256 + threadIdx.x;
    if (e < NE) {
        int p = atomicAdd(&cur[dst[e]], 1);
        int2 v; v.x = e; v.y = src[e];
        ps[p] = v;
    }
}

// ---------------------------------------------------------------------------
// W pre-split, both layers in one launch:
// W[k][n] f32 -> Wt_hi[n][k], Wt_lo[n][k] bf16
// ---------------------------------------------------------------------------
__global__ __launch_bounds__(256) void k_wsplit2(const float* __restrict__ W1,
                                                 const float* __restrict__ W2,
                                                 short* __restrict__ W1h,
                                                 short* __restrict__ W1l,
                                                 short* __restrict__ W2h,
                                                 short* __restrict__ W2l) {
    for (int t = blockIdx.x * 256 + threadIdx.x; t < 2 * D * D; t += gridDim.x * 256) {
        int which = t >= D * D;
        int idx = t - which * D * D;
        int n = idx >> 7, k = idx & 127;
        const float* W = which ? W2 : W1;
        float w = W[k * D + n];
        short hi = f2bf(w);
        short lo = f2bf(w - bf2f(hi));
        if (which) { W2h[idx] = hi; W2l[idx] = lo; }
        else       { W1h[idx] = hi; W1l[idx] = lo; }
    }
}

// ---------------------------------------------------------------------------
// Fused aggregation + 2-layer MLP. 32 nodes/block, 4 waves.
// Inter-phase tiles in bf16 LDS:
//   G1h/G1l: hi/lo split of aggregated h (bit-identical math to r7's split,
//            just performed at phase-1 store instead of phase-2a load)
//   G2     : layer-1 output, single bf16 (as r7 consumed it)
// LDS = 3 * 32*136*2 = 25.5 KB -> 6 blocks/CU (was 4), VGPR unchanged.
// LDGb=136 shorts: row stride 272 B = 17*16 B -> A-fragment ds_read_b128
// spreads over all 8 bank-groups (~2-way).
// ---------------------------------------------------------------------------
constexpr int LDGb = 136;  // bf16 row stride (shorts)

__global__ __launch_bounds__(256) void k_fused(const float* __restrict__ x,
                                               const float* __restrict__ ea,
                                               const int* __restrict__ off,
                                               const int2* __restrict__ ps,
                                               const float* __restrict__ eps,
                                               const short* __restrict__ W1h,
                                               const short* __restrict__ W1l,
                                               const short* __restrict__ W2h,
                                               const short* __restrict__ W2l,
                                               const float* __restrict__ b1,
                                               const float* __restrict__ b2,
                                               float* __restrict__ out) {
    __shared__ short G1h[32 * LDGb];  // 8704 B
    __shared__ short G1l[32 * LDGb];  // 8704 B
    __shared__ short G2 [32 * LDGb];  // 8704 B

    const int wave = threadIdx.x >> 6;
    const int lane = threadIdx.x & 63;
    const int nb = blockIdx.x * 32;

    // ---------------- phase 1: gather-aggregate 8 nodes per wave ----------
    // (byte-identical loop shape to r7 -> same VGPR/depth schedule)
    {
        const int lo2 = lane * 2;
        const float sc = 1.0f + eps[0];
        for (int t = 0; t < 8; ++t) {
            const int n = nb + wave * 8 + t;
            const int j0 = off[n], j1 = off[n + 1];
            float accx = 0.0f, accy = 0.0f;
            for (int j = j0; j < j1; j += 8) {
                int ee[8], ss[8];
#pragma unroll
                for (int q = 0; q < 8; ++q) {
                    int jj = j + q; jj = (jj < j1) ? jj : (j1 - 1);
                    int2 p = ps[jj];
                    ee[q] = p.x; ss[q] = p.y;
                }
                float2 xa[8], eb[8];
#pragma unroll
                for (int q = 0; q < 8; ++q) {
                    xa[q] = *reinterpret_cast<const float2*>(x  + (size_t)ss[q] * D + lo2);
                    eb[q] = *reinterpret_cast<const float2*>(ea + (size_t)ee[q] * D + lo2);
                }
#pragma unroll
                for (int q = 0; q < 8; ++q) {
                    float mx = fmaxf(xa[q].x + eb[q].x, 0.0f);
                    float my = fmaxf(xa[q].y + eb[q].y, 0.0f);
                    bool ok = (j + q) < j1;
                    accx += ok ? mx : 0.0f;
                    accy += ok ? my : 0.0f;
                }
            }
            float2 xx = *reinterpret_cast<const float2*>(x + (size_t)n * D + lo2);
            float ox = fmaf(sc, xx.x, accx);
            float oy = fmaf(sc, xx.y, accy);
            // hi/lo split at store time (same values r7 produced at load time)
            unsigned h = cvtpk(ox, oy);
            short h0 = (short)(h & 0xFFFF), h1 = (short)(h >> 16);
            unsigned l = cvtpk(ox - bf2f(h0), oy - bf2f(h1));
            const int row = wave * 8 + t;
            *reinterpret_cast<unsigned*>(&G1h[row * LDGb + lo2]) = h;
            *reinterpret_cast<unsigned*>(&G1l[row * LDGb + lo2]) = l;
        }
    }
    __syncthreads();

    const int r = lane & 15;   // A-row / W-col within 16-tile
    const int g = lane >> 4;   // k-group (8 k) / D-row group (4 rows)

    // ---------------- phase 2a: layer 1 (3-term bf16 MFMA) ----------------
    {
        f32x4 acc[2][2];
#pragma unroll
        for (int mt = 0; mt < 2; ++mt)
#pragma unroll
            for (int nl = 0; nl < 2; ++nl) {
                acc[mt][nl].x = 0.f; acc[mt][nl].y = 0.f;
                acc[mt][nl].z = 0.f; acc[mt][nl].w = 0.f;
            }

#pragma unroll
        for (int kc = 0; kc < 4; ++kc) {
            const int k0 = kc * 32;
            bf16x8 ahi[2], alo[2];
#pragma unroll
            for (int mt = 0; mt < 2; ++mt) {
                const int gb = (mt * 16 + r) * LDGb + k0 + g * 8;
                ahi[mt] = *reinterpret_cast<const bf16x8*>(&G1h[gb]);
                alo[mt] = *reinterpret_cast<const bf16x8*>(&G1l[gb]);
            }
#pragma unroll
            for (int nl = 0; nl < 2; ++nl) {
                const int nt = wave * 2 + nl;
                const int wb = (nt * 16 + r) * D + k0 + g * 8;
                bf16x8 whi = *reinterpret_cast<const bf16x8*>(&W1h[wb]);
                bf16x8 wlo = *reinterpret_cast<const bf16x8*>(&W1l[wb]);
#pragma unroll
                for (int mt = 0; mt < 2; ++mt) {
                    acc[mt][nl] = __builtin_amdgcn_mfma_f32_16x16x32_bf16(ahi[mt], whi, acc[mt][nl], 0, 0, 0);
                    acc[mt][nl] = __builtin_amdgcn_mfma_f32_16x16x32_bf16(ahi[mt], wlo, acc[mt][nl], 0, 0, 0);
                    acc[mt][nl] = __builtin_amdgcn_mfma_f32_16x16x32_bf16(alo[mt], whi, acc[mt][nl], 0, 0, 0);
                }
            }
        }

        // epilogue: bias + relu -> G2 bf16 (row = mt*16 + g*4 + q, col = nt*16 + r)
#pragma unroll
        for (int nl = 0; nl < 2; ++nl) {
            const int col = (wave * 2 + nl) * 16 + r;
            const float bb = b1[col];
#pragma unroll
            for (int mt = 0; mt < 2; ++mt)
#pragma unroll
                for (int q = 0; q < 4; ++q)
                    G2[(mt * 16 + g * 4 + q) * LDGb + col] =
                        f2bf(fmaxf(acc[mt][nl][q] + bb, 0.0f));
        }
    }
    __syncthreads();

    // ---------------- phase 2b: layer 2 (2-term, single-bf16 A) -----------
    {
        f32x4 acc[2][2];
#pragma unroll
        for (int mt = 0; mt < 2; ++mt)
#pragma unroll
            for (int nl = 0; nl < 2; ++nl) {
                acc[mt][nl].x = 0.f; acc[mt][nl].y = 0.f;
                acc[mt][nl].z = 0.f; acc[mt][nl].w = 0.f;
            }

#pragma unroll
        for (int kc = 0; kc < 4; ++kc) {
            const int k0 = kc * 32;
            bf16x8 a[2];
#pragma unroll
            for (int mt = 0; mt < 2; ++mt)
                a[mt] = *reinterpret_cast<const bf16x8*>(&G2[(mt * 16 + r) * LDGb + k0 + g * 8]);
#pragma unroll
            for (int nl = 0; nl < 2; ++nl) {
                const int nt = wave * 2 + nl;
                const int wb = (nt * 16 + r) * D + k0 + g * 8;
                bf16x8 whi = *reinterpret_cast<const bf16x8*>(&W2h[wb]);
                bf16x8 wlo = *reinterpret_cast<const bf16x8*>(&W2l[wb]);
#pragma unroll
                for (int mt = 0; mt < 2; ++mt) {
                    acc[mt][nl] = __builtin_amdgcn_mfma_f32_16x16x32_bf16(a[mt], whi, acc[mt][nl], 0, 0, 0);
                    acc[mt][nl] = __builtin_amdgcn_mfma_f32_16x16x32_bf16(a[mt], wlo, acc[mt][nl], 0, 0, 0);
                }
            }
        }

#pragma unroll
        for (int nl = 0; nl < 2; ++nl) {
            const int col = (wave * 2 + nl) * 16 + r;
            const float bb = b2[col];
#pragma unroll
            for (int mt = 0; mt < 2; ++mt)
#pragma unroll
                for (int q = 0; q < 4; ++q) {
                    long row = nb + mt * 16 + g * 4 + q;
                    out[row * D + col] = acc[mt][nl][q] + bb;
                }
        }
    }
}

// ---------------------------------------------------------------------------
extern "C" void kernel_launch(void* const* d_in, const int* in_sizes, int n_in,
                              void* d_out, int out_size, void* d_ws, size_t ws_size,
                              hipStream_t stream) {
    const float* x   = (const float*)d_in[0];
    const int*   ei  = (const int*)d_in[1];   // int32 [2, NE]
    const float* ea  = (const float*)d_in[2];
    const float* eps = (const float*)d_in[3];
    const float* W1  = (const float*)d_in[4];
    const float* b1  = (const float*)d_in[5];
    const float* W2  = (const float*)d_in[6];
    const float* b2  = (const float*)d_in[7];
    float* out = (float*)d_out;

    const int* src = ei;
    const int* dst = ei + NE;

    // ws layout (~6.5 MB)
    int* base  = (int*)d_ws;
    int* cnt   = base;                 // NN
    int* off   = cnt + NN;             // NN+1
    int* cur   = off + NN + 1;         // NN
    int* bsum  = cur + NN;             // NB
    int* bboff = bsum + NB;            // NB
    size_t ps_off = ((size_t)(3 * NN + 1 + 2 * NB) + 1) & ~(size_t)1;
    int2* ps   = (int2*)(base + ps_off);               // NE int2
    short* wsp = (short*)(base + ps_off + 2 * (size_t)NE);
    short* W1h = wsp;                  // D*D each
    short* W1l = W1h + D * D;
    short* W2h = W1l + D * D;
    short* W2l = W2h + D * D;

    k_wsplit2   <<<64,               256, 0, stream>>>(W1, W2, W1h, W1l, W2h, W2l);
    k_zero      <<<NB,               256, 0, stream>>>(cnt);
    k_hist      <<<(NE + 255) / 256, 256, 0, stream>>>(dst, cnt);
    k_bsum      <<<NB,               256, 0, stream>>>(cnt, bsum);
    k_scan_bsum <<<1,                512, 0, stream>>>(bsum, bboff);
    k_scan_final<<<NB,               256, 0, stream>>>(cnt, bboff, off, cur);
    k_perm      <<<(NE + 255) / 256, 256, 0, stream>>>(dst, src, cur, ps);

    // fused: gather-aggregate -> bf16 LDS tiles -> 2-layer MFMA MLP -> out
    k_fused<<<NN / 32, 256, 0, stream>>>(x, ea, off, ps, eps,
                                         W1h, W1l, W2h, W2l, b1, b2, out);
}